// Round 5
// baseline (1397.986 us; speedup 1.0000x reference)
//
#include <hip/hip_runtime.h>

#define NB    32
#define SEQ   128
#define WCH   20
#define CED   50
#define NFLT  64
#define WDIM  300
#define HD    512
#define NWORD 4096
#define LPAD  11
#define NEGV  -10000.0f
#define LSTM_BLOCKS 16

typedef float f32x4 __attribute__((ext_vector_type(4)));
typedef float f32x16 __attribute__((ext_vector_type(16)));
typedef __bf16 bf16x8 __attribute__((ext_vector_type(8)));
typedef unsigned short u16x8 __attribute__((ext_vector_type(8)));
typedef unsigned short u16x4 __attribute__((ext_vector_type(4)));
typedef unsigned long long ull;

static __device__ __forceinline__ unsigned short f2bf(float f) {
  unsigned u = __builtin_bit_cast(unsigned, f);
  u += 0x7fffu + ((u >> 16) & 1u);
  return (unsigned short)(u >> 16);
}
static __device__ __forceinline__ float bf2f(unsigned short s) {
  unsigned u = ((unsigned)s) << 16;
  return __builtin_bit_cast(float, u);
}
static __device__ __forceinline__ float sigf(float x) { return 1.0f / (1.0f + expf(-x)); }

// ---------------------------------------------------------------- char CNN
__global__ __launch_bounds__(256) void conv_kernel(
    const int* __restrict__ char_ids, const float* __restrict__ char_embed,
    const float* __restrict__ w2, const float* __restrict__ b2,
    const float* __restrict__ w3, const float* __restrict__ b3,
    const float* __restrict__ w4, const float* __restrict__ b4,
    const float* __restrict__ w5, const float* __restrict__ b5,
    float* __restrict__ ch)
{
  __shared__ __align__(16) float xT[CED][WCH];
  int wi = blockIdx.x;
  int tid = threadIdx.x;
  for (int e = tid; e < WCH * CED; e += 256) {
    int p = e / CED, c = e - p * CED;
    int cid = char_ids[wi * WCH + p];
    xT[c][p] = char_embed[cid * CED + c];
  }
  __syncthreads();
  int w = tid >> 6, f = tid & 63;
  int k = w + 2;
  int P = WCH - k + 1;
  const float* cw = (w == 0) ? w2 : (w == 1) ? w3 : (w == 2) ? w4 : w5;
  const float* cb = (w == 0) ? b2 : (w == 1) ? b3 : (w == 2) ? b4 : b5;
  float acc[19];
  #pragma unroll
  for (int p = 0; p < 19; p++) acc[p] = 0.f;
  for (int c = 0; c < CED; c++) {
    float xr[20];
    const float4* rowp = (const float4*)&xT[c][0];
    #pragma unroll
    for (int q = 0; q < 5; q++) {
      float4 v = rowp[q];
      xr[4*q+0] = v.x; xr[4*q+1] = v.y; xr[4*q+2] = v.z; xr[4*q+3] = v.w;
    }
    #pragma unroll
    for (int dw = 0; dw < 5; dw++) {
      if (dw < k) {
        float wv = cw[(dw * CED + c) * NFLT + f];
        #pragma unroll
        for (int p = 0; p < 19; p++) {
          if (p < P) acc[p] += xr[p + dw] * wv;
        }
      }
    }
  }
  float m = acc[0];
  #pragma unroll
  for (int p = 1; p < 19; p++) if (p < P) m = fmaxf(m, acc[p]);
  ch[wi * 256 + w * 64 + f] = fmaxf(0.f, m + cb[f]);
}

// ---------------------------------------------------------------- word gather
__global__ void gather_word_kernel(const int* __restrict__ token_ids,
                                   const float* __restrict__ word_embed,
                                   float* __restrict__ word_in)
{
  int idx = blockIdx.x * 256 + threadIdx.x;
  if (idx < NWORD * WDIM) {
    int i = idx / WDIM, c = idx - i * WDIM;
    word_in[idx] = word_embed[token_ids[i] * WDIM + c];
  }
}

// ---------------------------------------------------------------- generic MFMA GEMM: C = act(A @ B^T + Cin + bias)
__global__ __launch_bounds__(256) void gemm_bt_kernel(
    const float* __restrict__ A, const float* __restrict__ Bw,
    const float* __restrict__ bias, const float* __restrict__ Cin,
    float* __restrict__ Cout, unsigned short* __restrict__ Cbf,
    int M, int N, int K, int act, int gridN)
{
  __shared__ __align__(16) unsigned short As[128 * 32];
  __shared__ __align__(16) unsigned short Bs[128 * 32];
  int bid = blockIdx.x;
  int tm = bid / gridN, tn = bid - tm * gridN;
  int m0 = tm * 128, n0 = tn * 128;
  int tid = threadIdx.x;
  int lane = tid & 63, w = tid >> 6;
  int wr = (w >> 1) * 64, wc = (w & 1) * 64;
  f32x4 acc[4][4] = {};
  int fr = lane & 15, fk = (lane >> 4) * 8;

  for (int k0 = 0; k0 < K; k0 += 32) {
    __syncthreads();
    #pragma unroll
    for (int i = 0; i < 4; i++) {
      int idx = tid + i * 256;
      int r = idx >> 3, c4 = idx & 7;
      int kx = k0 + c4 * 4;
      int ra = m0 + r, rb = n0 + r;
      f32x4 av = {0.f,0.f,0.f,0.f}, bv = {0.f,0.f,0.f,0.f};
      if (kx < K) {
        if (ra < M) av = *(const f32x4*)&A[(size_t)ra * K + kx];
        if (rb < N) bv = *(const f32x4*)&Bw[(size_t)rb * K + kx];
      }
      u16x4 ap, bp;
      #pragma unroll
      for (int j = 0; j < 4; j++) { ap[j] = f2bf(av[j]); bp[j] = f2bf(bv[j]); }
      *(u16x4*)&As[r * 32 + c4 * 4] = ap;
      *(u16x4*)&Bs[r * 32 + c4 * 4] = bp;
    }
    __syncthreads();
    bf16x8 a[4], b[4];
    #pragma unroll
    for (int mt = 0; mt < 4; mt++)
      a[mt] = *(const bf16x8*)&As[(wr + mt * 16 + fr) * 32 + fk];
    #pragma unroll
    for (int nt = 0; nt < 4; nt++)
      b[nt] = *(const bf16x8*)&Bs[(wc + nt * 16 + fr) * 32 + fk];
    #pragma unroll
    for (int mt = 0; mt < 4; mt++)
      #pragma unroll
      for (int nt = 0; nt < 4; nt++)
        acc[mt][nt] = __builtin_amdgcn_mfma_f32_16x16x32_bf16(a[mt], b[nt], acc[mt][nt], 0, 0, 0);
  }

  #pragma unroll
  for (int mt = 0; mt < 4; mt++) {
    #pragma unroll
    for (int nt = 0; nt < 4; nt++) {
      #pragma unroll
      for (int j = 0; j < 4; j++) {
        int row = m0 + wr + mt * 16 + (lane >> 4) * 4 + j;
        int col = n0 + wc + nt * 16 + (lane & 15);
        if (row < M && col < N) {
          float v = acc[mt][nt][j];
          if (Cin)  v += Cin[(size_t)row * N + col];
          if (bias) v += bias[col];
          if (act == 1)      v = tanhf(v);
          else if (act == 2) v = sigf(v);
          if (Cbf) Cbf[(size_t)row * N + col] = f2bf(v);
          else     Cout[(size_t)row * N + col] = v;
        }
      }
    }
  }
}

// ---------------------------------------------------------------- gate combine (+ flag reset)
__global__ void feats_kernel(const float* __restrict__ g, const float* __restrict__ word_in,
                             const float* __restrict__ char_in, float* __restrict__ feats,
                             unsigned* __restrict__ flags)
{
  if (blockIdx.x == 0 && threadIdx.x < 32)
    __hip_atomic_store(&flags[threadIdx.x], 0u, __ATOMIC_RELAXED, __HIP_MEMORY_SCOPE_AGENT);
  int idx = blockIdx.x * 256 + threadIdx.x;
  if (idx < NWORD * WDIM) {
    float gg = g[idx];
    feats[idx] = gg * word_in[idx] + (1.f - gg) * char_in[idx];
  }
}

// ---------------------------------------------------------------- bidirectional LSTM
// 16 blocks x 512 thr; block owns units [sl*32, sl*32+32) for BOTH dirs (ping-pong).
// Wave w: gate g=w&3, K-half kh=w>>2. wfF/wfB VGPR-resident (128 VGPR).
// h exchange via agent-scope (L3-coherent) atomics. Each dir's flag round-trip and
// staging latency hide under the other dir's compute phase.
// flags[0..15]=fwd, flags[16..31]=bwd (monotonic step counters, separate 64B lines).
__global__ __launch_bounds__(512, 2) void lstm_kernel(
    const unsigned short* __restrict__ xg_f, const unsigned short* __restrict__ xg_b,
    const float* __restrict__ whh_f, const float* __restrict__ whh_b,
    const int* __restrict__ lens,
    float* __restrict__ lstm_out, unsigned short* __restrict__ h_glob,
    unsigned* __restrict__ flags)
{
  int sl = blockIdx.x;
  int hs0 = sl << 5;                       // 32 units per dir
  int tid = threadIdx.x, lane = tid & 63, w = tid >> 6;
  int g = w & 3, kh = w >> 2;
  int l31 = lane & 31, le = lane >> 5;

  unsigned short* hgF = h_glob;                    // [2][NB*HD]
  unsigned short* hgB = h_glob + 2 * NB * HD;

  // B-fragments: whh row (unit) = g*HD + hs0 + l31 ; k = kh*256 + kk*16 + le*8 + j
  bf16x8 wfF[16], wfB[16];
  {
    const float* sF = whh_f + (size_t)(g * HD + hs0 + l31) * HD + kh * 256 + le * 8;
    const float* sB = whh_b + (size_t)(g * HD + hs0 + l31) * HD + kh * 256 + le * 8;
    #pragma unroll
    for (int kk = 0; kk < 16; kk++) {
      u16x8 tf_, tb_;
      #pragma unroll
      for (int j = 0; j < 8; j++) { tf_[j] = f2bf(sF[kk * 16 + j]); tb_[j] = f2bf(sB[kk * 16 + j]); }
      wfF[kk] = __builtin_bit_cast(bf16x8, tf_);
      wfB[kk] = __builtin_bit_cast(bf16x8, tb_);
    }
  }

  __shared__ __align__(16) unsigned short hS[16384];   // 32KB fragment-major (shared F/B)
  __shared__ float Gs[2][NB][132];                     // K-half partial pre-activations

  int b = tid >> 4, up = tid & 15;         // update: batch, unit-pair
  int srow = tid >> 4, sq = tid & 15;      // staging: h row, 64B quad
  int mylen = lens[b];
  float cF[2] = {0.f,0.f}, hpF[2] = {0.f,0.f};
  float cB[2] = {0.f,0.f}, hpB[2] = {0.f,0.f};

  ull hr[8];                               // staging regs (time-shared F/B)

  auto stage_issue = [&](const unsigned short* hbuf) {
    const ull* hq = (const ull*)hbuf;
    #pragma unroll
    for (int i = 0; i < 8; i++)
      hr[i] = __hip_atomic_load(hq + srow * 128 + sq * 8 + i, __ATOMIC_RELAXED, __HIP_MEMORY_SCOPE_AGENT);
  };
  auto stage_write = [&]() {
    int rs = ((srow ^ (sq & 7)) & 31) << 4;
    #pragma unroll
    for (int e2 = 0; e2 < 4; e2++) {
      int kk = 2 * sq + (e2 >> 1), e = e2 & 1;
      uint4 qv;
      qv.x = (unsigned)hr[2*e2];   qv.y = (unsigned)(hr[2*e2] >> 32);
      qv.z = (unsigned)hr[2*e2+1]; qv.w = (unsigned)(hr[2*e2+1] >> 32);
      *(uint4*)((char*)hS + (((kk * 2 + e) << 9) + rs)) = qv;
    }
  };
  auto wait_flags = [&](int base, unsigned target) {
    if (tid == 0) {
      const ull* fp = (const ull*)(flags + base);
      for (;;) {
        unsigned mn = 0xffffffffu;
        #pragma unroll
        for (int i = 0; i < 8; i++) {
          ull v = __hip_atomic_load(fp + i, __ATOMIC_RELAXED, __HIP_MEMORY_SCOPE_AGENT);
          unsigned a = (unsigned)v, bq = (unsigned)(v >> 32);
          mn = a < mn ? a : mn; mn = bq < mn ? bq : mn;
        }
        if (mn >= target) break;
        __builtin_amdgcn_s_sleep(1);
      }
    }
  };

  // xg preload for s=0
  unsigned xF[4], xB[4];
  {
    const unsigned* pF = (const unsigned*)xg_f;
    const unsigned* pB = (const unsigned*)xg_b;
    size_t oF = (size_t)(b * SEQ + 0) * 1024 + (hs0 >> 1) + up;
    size_t oB = (size_t)(b * SEQ + (SEQ - 1)) * 1024 + (hs0 >> 1) + up;
    #pragma unroll
    for (int g4 = 0; g4 < 4; g4++) { xF[g4] = pF[oF + g4 * 256]; xB[g4] = pB[oB + g4 * 256]; }
  }

  for (int s = 0; s < SEQ; s++) {
    int tf_ = s, tb_ = SEQ - 1 - s;
    // ================= F phase =================
    if (s > 0) stage_write();                 // f-h(s-1) regs -> LDS
    __syncthreads();
    {
      f32x16 acc = {};
      if (s > 0) {
        #pragma unroll
        for (int q = 0; q < 16; q++) {
          int kk = kh * 16 + q;
          int rs = ((l31 ^ ((kk >> 1) & 7)) & 31) << 4;
          bf16x8 a = *(const bf16x8*)((const char*)hS + (((kk * 2 + le) << 9) + rs));
          acc = __builtin_amdgcn_mfma_f32_32x32x16_bf16(a, wfF[q], acc, 0, 0, 0);
        }
      }
      #pragma unroll
      for (int r = 0; r < 16; r++) {
        int row = (r & 3) + 8 * (r >> 2) + 4 * le;
        Gs[kh][row][g * 32 + l31] = acc[r];
      }
    }
    if (s > 0) wait_flags(16, (unsigned)s);    // b-flags >= s (published ~1 phase ago)
    __syncthreads();                           // Gs ready + detect released
    if (s > 0) stage_issue(hgB + (s & 1) * (NB * HD));   // b-h(s-1) loads (overlap f-gates)
    {
      bool mk = (tf_ < mylen);
      float pre[4][2];
      #pragma unroll
      for (int g4 = 0; g4 < 4; g4++) {
        float2 p0 = *(const float2*)&Gs[0][b][g4 * 32 + 2 * up];
        float2 p1 = *(const float2*)&Gs[1][b][g4 * 32 + 2 * up];
        pre[g4][0] = p0.x + p1.x; pre[g4][1] = p0.y + p1.y;
      }
      float2 ov; unsigned pk = 0;
      #pragma unroll
      for (int j = 0; j < 2; j++) {
        float xi = bf2f((unsigned short)(xF[0] >> (16*j)));
        float xf = bf2f((unsigned short)(xF[1] >> (16*j)));
        float xG = bf2f((unsigned short)(xF[2] >> (16*j)));
        float xo = bf2f((unsigned short)(xF[3] >> (16*j)));
        float iv = sigf(xi + pre[0][j]);
        float fv = sigf(xf + pre[1][j]);
        float Gv = tanhf(xG + pre[2][j]);
        float o_ = sigf(xo + pre[3][j]);
        float cn = fv * cF[j] + iv * Gv;
        float hh = o_ * tanhf(cn);
        if (mk) cF[j] = cn;
        float hk = mk ? hh : hpF[j];
        hpF[j] = hk;
        (&ov.x)[j] = mk ? hh : 0.f;
        pk |= ((unsigned)f2bf(hk)) << (16*j);
      }
      size_t ob = (size_t)(b * SEQ + tf_) * 1024 + hs0 + 2 * up;
      *(float2*)&lstm_out[ob] = ov;
      unsigned* hd = (unsigned*)(hgF + ((s & 1) ^ 1) * (NB * HD));
      __hip_atomic_store(&hd[(b * HD + hs0 + 2 * up) >> 1], pk, __ATOMIC_RELAXED, __HIP_MEMORY_SCOPE_AGENT);
    }
    __syncthreads();                           // drains h_f stores (and b-stage loads)
    if (tid == 0)
      __hip_atomic_store(&flags[sl], (unsigned)(s + 1), __ATOMIC_RELAXED, __HIP_MEMORY_SCOPE_AGENT);
    if (s + 1 < SEQ) {                         // xF prefetch overlaps B phase
      const unsigned* pF = (const unsigned*)xg_f;
      size_t oF = (size_t)(b * SEQ + (s + 1)) * 1024 + (hs0 >> 1) + up;
      #pragma unroll
      for (int g4 = 0; g4 < 4; g4++) xF[g4] = pF[oF + g4 * 256];
    }
    // ================= B phase =================
    if (s > 0) stage_write();                 // b-h(s-1) regs -> LDS
    __syncthreads();
    {
      f32x16 acc = {};
      if (s > 0) {
        #pragma unroll
        for (int q = 0; q < 16; q++) {
          int kk = kh * 16 + q;
          int rs = ((l31 ^ ((kk >> 1) & 7)) & 31) << 4;
          bf16x8 a = *(const bf16x8*)((const char*)hS + (((kk * 2 + le) << 9) + rs));
          acc = __builtin_amdgcn_mfma_f32_32x32x16_bf16(a, wfB[q], acc, 0, 0, 0);
        }
      }
      #pragma unroll
      for (int r = 0; r < 16; r++) {
        int row = (r & 3) + 8 * (r >> 2) + 4 * le;
        Gs[kh][row][g * 32 + l31] = acc[r];
      }
    }
    if (s + 1 < SEQ) wait_flags(0, (unsigned)(s + 1));   // f-flags >= s+1
    __syncthreads();
    if (s + 1 < SEQ) stage_issue(hgF + ((s + 1) & 1) * (NB * HD));  // f-h(s) loads
    {
      bool mk = (tb_ < mylen);
      float pre[4][2];
      #pragma unroll
      for (int g4 = 0; g4 < 4; g4++) {
        float2 p0 = *(const float2*)&Gs[0][b][g4 * 32 + 2 * up];
        float2 p1 = *(const float2*)&Gs[1][b][g4 * 32 + 2 * up];
        pre[g4][0] = p0.x + p1.x; pre[g4][1] = p0.y + p1.y;
      }
      float2 ov; unsigned pk = 0;
      #pragma unroll
      for (int j = 0; j < 2; j++) {
        float xi = bf2f((unsigned short)(xB[0] >> (16*j)));
        float xf = bf2f((unsigned short)(xB[1] >> (16*j)));
        float xG = bf2f((unsigned short)(xB[2] >> (16*j)));
        float xo = bf2f((unsigned short)(xB[3] >> (16*j)));
        float iv = sigf(xi + pre[0][j]);
        float fv = sigf(xf + pre[1][j]);
        float Gv = tanhf(xG + pre[2][j]);
        float o_ = sigf(xo + pre[3][j]);
        float cn = fv * cB[j] + iv * Gv;
        float hh = o_ * tanhf(cn);
        if (mk) cB[j] = cn;
        float hk = mk ? hh : hpB[j];
        hpB[j] = hk;
        (&ov.x)[j] = mk ? hh : 0.f;
        pk |= ((unsigned)f2bf(hk)) << (16*j);
      }
      size_t ob = (size_t)(b * SEQ + tb_) * 1024 + HD + hs0 + 2 * up;
      *(float2*)&lstm_out[ob] = ov;
      unsigned* hd = (unsigned*)(hgB + ((s & 1) ^ 1) * (NB * HD));
      __hip_atomic_store(&hd[(b * HD + hs0 + 2 * up) >> 1], pk, __ATOMIC_RELAXED, __HIP_MEMORY_SCOPE_AGENT);
    }
    __syncthreads();                           // drains h_b stores (and f-stage loads)
    if (tid == 0)
      __hip_atomic_store(&flags[16 + sl], (unsigned)(s + 1), __ATOMIC_RELAXED, __HIP_MEMORY_SCOPE_AGENT);
    if (s + 1 < SEQ) {                         // xB prefetch overlaps next F phase
      const unsigned* pB = (const unsigned*)xg_b;
      size_t oB = (size_t)(b * SEQ + (SEQ - 2 - s)) * 1024 + (hs0 >> 1) + up;
      #pragma unroll
      for (int g4 = 0; g4 < 4; g4++) xB[g4] = pB[oB + g4 * 256];
    }
  }
}

// ---------------------------------------------------------------- output projection + NEG pads
__global__ __launch_bounds__(64) void logits_kernel(
    const float* __restrict__ lstm_out, const float* __restrict__ out_w,
    const float* __restrict__ out_b, float* __restrict__ lg)
{
  int rw = blockIdx.x, j = threadIdx.x;
  const float* row = lstm_out + (size_t)rw * 1024;
  float s[9];
  #pragma unroll
  for (int l = 0; l < 9; l++) s[l] = 0.f;
  for (int e = j; e < 1024; e += 64) {
    float x = row[e];
    #pragma unroll
    for (int l = 0; l < 9; l++) s[l] += x * out_w[l * 1024 + e];
  }
  #pragma unroll
  for (int l = 0; l < 9; l++) {
    #pragma unroll
    for (int off = 32; off > 0; off >>= 1) s[l] += __shfl_xor(s[l], off);
  }
  float v = NEGV;
  if (j < 9) {
    float r = (j==0)?s[0]:(j==1)?s[1]:(j==2)?s[2]:(j==3)?s[3]:(j==4)?s[4]:
              (j==5)?s[5]:(j==6)?s[6]:(j==7)?s[7]:s[8];
    v = r + out_b[j];
  }
  if (j < LPAD) lg[(size_t)rw * LPAD + j] = v;
}

// ---------------------------------------------------------------- CRF gold score
__global__ __launch_bounds__(64) void crf_gold_kernel(
    const float* __restrict__ lg, const int* __restrict__ labels,
    const int* __restrict__ lens, const float* __restrict__ trn, float* __restrict__ gold)
{
  int b = blockIdx.x, j = threadIdx.x;
  int len = lens[b];
  const int* lab = labels + b * SEQ;
  const float* l0 = lg + (size_t)b * SEQ * LPAD;
  float s = 0.f;
  for (int t = j; t < SEQ; t += 64) {
    if (t < len) {
      s += l0[t * LPAD + lab[t]];
      if (t >= 1) s += trn[lab[t] * LPAD + lab[t - 1]];
    }
  }
  #pragma unroll
  for (int off = 32; off > 0; off >>= 1) s += __shfl_xor(s, off);
  if (j == 0) {
    s += trn[lab[0] * LPAD + 9];
    s += trn[10 * LPAD + lab[len - 1]];
    gold[b] = s;
  }
}

// ---------------------------------------------------------------- CRF norm + final loglik
__global__ __launch_bounds__(64) void crf_norm_kernel(
    const float* __restrict__ lg, const int* __restrict__ lens,
    const float* __restrict__ trn, const float* __restrict__ gold, float* __restrict__ out_ll)
{
  int b = blockIdx.x, i = threadIdx.x;
  int len = lens[b];
  const float* l0 = lg + (size_t)b * SEQ * LPAD;
  bool act = (i < LPAD);
  float trow[LPAD];
  #pragma unroll
  for (int jj = 0; jj < LPAD; jj++) trow[jj] = act ? trn[i * LPAD + jj] : 0.f;
  float alpha = act ? (l0[i] + trow[9]) : -1e30f;

  for (int t = 1; t < SEQ; t++) {
    float vj[LPAD];
    #pragma unroll
    for (int jj = 0; jj < LPAD; jj++) vj[jj] = __shfl(alpha, jj) + trow[jj];
    float mx = vj[0];
    #pragma unroll
    for (int jj = 1; jj < LPAD; jj++) mx = fmaxf(mx, vj[jj]);
    float sum = 0.f;
    #pragma unroll
    for (int jj = 0; jj < LPAD; jj++) sum += expf(vj[jj] - mx);
    float lgv = act ? l0[t * LPAD + i] : 0.f;
    float nw = mx + logf(sum) + lgv;
    if (act && t < len) alpha = nw;
  }
  float vj[LPAD];
  #pragma unroll
  for (int jj = 0; jj < LPAD; jj++) vj[jj] = __shfl(alpha, jj) + trn[10 * LPAD + jj];
  float mx = vj[0];
  #pragma unroll
  for (int jj = 1; jj < LPAD; jj++) mx = fmaxf(mx, vj[jj]);
  float sum = 0.f;
  #pragma unroll
  for (int jj = 0; jj < LPAD; jj++) sum += expf(vj[jj] - mx);
  if (i == 0) out_ll[b] = gold[b] - (mx + logf(sum));
}

// ================================================================ launch
extern "C" void kernel_launch(void* const* d_in, const int* in_sizes, int n_in,
                              void* d_out, int out_size, void* d_ws, size_t ws_size,
                              hipStream_t stream)
{
  (void)in_sizes; (void)n_in; (void)out_size; (void)ws_size;
  const int*   token_ids = (const int*)d_in[0];
  const int*   char_ids  = (const int*)d_in[1];
  const int*   lens      = (const int*)d_in[2];
  const int*   labels    = (const int*)d_in[3];
  const float* word_embed= (const float*)d_in[4];
  const float* char_embed= (const float*)d_in[5];
  const float* w2 = (const float*)d_in[6];  const float* cb2 = (const float*)d_in[7];
  const float* w3 = (const float*)d_in[8];  const float* cb3 = (const float*)d_in[9];
  const float* w4 = (const float*)d_in[10]; const float* cb4 = (const float*)d_in[11];
  const float* w5 = (const float*)d_in[12]; const float* cb5 = (const float*)d_in[13];
  const float* ff_w = (const float*)d_in[14]; const float* ff_b = (const float*)d_in[15];
  const float* wgate_w = (const float*)d_in[16];
  const float* cgate_w = (const float*)d_in[17];
  const float* gate_w  = (const float*)d_in[18];
  const float* wih_f = (const float*)d_in[19]; const float* whh_f = (const float*)d_in[20];
  const float* b_f   = (const float*)d_in[21];
  const float* wih_b = (const float*)d_in[22]; const float* whh_b = (const float*)d_in[23];
  const float* b_b   = (const float*)d_in[24];
  const float* out_w = (const float*)d_in[25]; const float* out_b = (const float*)d_in[26];
  const float* trn   = (const float*)d_in[27];

  char* ws = (char*)d_ws;
  size_t off = 0;
  auto alloc = [&](size_t bytes) { void* p = ws + off; off += (bytes + 255) & ~(size_t)255; return p; };
  float* ch       = (float*)alloc((size_t)NWORD * 256 * 4);
  float* word_in  = (float*)alloc((size_t)NWORD * WDIM * 4);
  float* char_in  = (float*)alloc((size_t)NWORD * WDIM * 4);
  float* t1       = (float*)alloc((size_t)NWORD * WDIM * 4);
  float* gbuf     = (float*)alloc((size_t)NWORD * WDIM * 4);
  float* feats    = (float*)alloc((size_t)NWORD * WDIM * 4);
  unsigned short* xgf = (unsigned short*)alloc((size_t)NWORD * 2048 * 2);
  unsigned short* xgb = (unsigned short*)alloc((size_t)NWORD * 2048 * 2);
  float* lstm_o   = (float*)alloc((size_t)NWORD * 1024 * 4);
  unsigned short* hglob = (unsigned short*)alloc((size_t)2 * 2 * NB * HD * 2);
  float* gold     = (float*)alloc((size_t)NB * 4);
  unsigned* flags = (unsigned*)alloc(256);

  float* outp   = (float*)d_out;
  float* loglik = outp;
  float* logits = outp + NB;

  conv_kernel<<<NWORD, 256, 0, stream>>>(char_ids, char_embed, w2, cb2, w3, cb3, w4, cb4, w5, cb5, ch);
  gather_word_kernel<<<(NWORD * WDIM + 255) / 256, 256, 0, stream>>>(token_ids, word_embed, word_in);
  gemm_bt_kernel<<<32 * 3, 256, 0, stream>>>(ch, ff_w, ff_b, nullptr, char_in, nullptr, NWORD, 300, 256, 0, 3);
  gemm_bt_kernel<<<32 * 3, 256, 0, stream>>>(word_in, wgate_w, nullptr, nullptr, t1, nullptr, NWORD, 300, 300, 0, 3);
  gemm_bt_kernel<<<32 * 3, 256, 0, stream>>>(char_in, cgate_w, nullptr, t1, t1, nullptr, NWORD, 300, 300, 1, 3);
  gemm_bt_kernel<<<32 * 3, 256, 0, stream>>>(t1, gate_w, nullptr, nullptr, gbuf, nullptr, NWORD, 300, 300, 2, 3);
  feats_kernel<<<(NWORD * WDIM + 255) / 256, 256, 0, stream>>>(gbuf, word_in, char_in, feats, flags);
  gemm_bt_kernel<<<32 * 16, 256, 0, stream>>>(feats, wih_f, b_f, nullptr, nullptr, xgf, NWORD, 2048, 300, 0, 16);
  gemm_bt_kernel<<<32 * 16, 256, 0, stream>>>(feats, wih_b, b_b, nullptr, nullptr, xgb, NWORD, 2048, 300, 0, 16);
  {
    void* args[] = { (void*)&xgf, (void*)&xgb, (void*)&whh_f, (void*)&whh_b,
                     (void*)&lens, (void*)&lstm_o, (void*)&hglob, (void*)&flags };
    hipLaunchCooperativeKernel((void*)lstm_kernel, dim3(LSTM_BLOCKS), dim3(512), args, 0, stream);
  }
  logits_kernel<<<NWORD, 64, 0, stream>>>(lstm_o, out_w, out_b, logits);
  crf_gold_kernel<<<NB, 64, 0, stream>>>(logits, labels, lens, trn, gold);
  crf_norm_kernel<<<NB, 64, 0, stream>>>(logits, lens, trn, gold, loglik);
}